// Round 1
// baseline (374.032 us; speedup 1.0000x reference)
//
#include <hip/hip_runtime.h>
#include <stdint.h>

// GNN layer, fp32, GEMM-restructured + CSR reduce:
//   prep: transpose weights into WT_ab[64][128], WT_c[32][64], WT_n[128][64]
//   gemm_ab: [A16|B16] = nf @ We[:,0:128]^T          (fp16 out, [N,64] each)
//   gemm_c:  C16 = ef @ We[:,128:160]^T              (fp16 out, [E,64])
//   CSR build: hist -> scan -> scatter, XCD-partitioned (blockIdx&7 owns a
//     node range; all stores/atomics for a line come from one XCD -> kills
//     the 8x partial-line writeback amplification measured in R5)
//     scatter stores BYTE offsets (src<<7, eid<<7) so reduce does no muls.
//   reduce:  red[v] = sum leaky(A16[u] + B16[v] + C16[e])   (fp32 acc)
//     wave = 4 incidences x 16 lanes x 4 ch/lane, dwordx2 gathers,
//     cross-group shfl_xor(16/32) finish. VMEM instrs/incidence: 3 -> 0.75.
//   apply:   out = leaky(nf @ Wn[:,0:64]^T + red @ Wn[:,64:128]^T)

#define LEAKY(x) fmaxf((x), 0.01f * (x))
typedef _Float16 f16;

static __device__ __forceinline__ int swz(int k, int c) {
    return k * 128 + (c ^ (((k >> 2) & 7) << 2));
}

union H4 { f16 h[4]; short4 s; long long ll; };

// ---------------- weight prep (transpose into ws) ----------------
__global__ void prep_weights_kernel(const float* __restrict__ We,
                                    const float* __restrict__ Wn,
                                    float* __restrict__ WTab,
                                    float* __restrict__ WTc,
                                    float* __restrict__ WTn)
{
    int i = blockIdx.x * blockDim.x + threadIdx.x;
    const int stride = gridDim.x * blockDim.x;
    for (; i < 8192 + 2048 + 8192; i += stride) {
        if (i < 8192) {
            int k = i >> 7, n = i & 127;
            WTab[i] = We[(n & 63) * 160 + (n >> 6) * 64 + k];
        } else if (i < 10240) {
            int j = i - 8192; int k = j >> 6, n = j & 63;
            WTc[j] = We[n * 160 + 128 + k];
        } else {
            int j = i - 10240; int k = j >> 6, n = j & 63;
            WTn[j] = Wn[n * 128 + k];
        }
    }
}

// ---------------- gemm_ab: [A|B] = nf @ WT_ab, tile 128x128, K=64 ----------------
__global__ __launch_bounds__(256) void gemm_ab_kernel(
    const float4* __restrict__ nf4, const float* __restrict__ WT,
    f16* __restrict__ A16, f16* __restrict__ B16, int M)
{
    __shared__ float As[64 * 128];
    __shared__ float Ws[64 * 128];
    const int t = threadIdx.x;
    const int tr = t >> 4, tc = t & 15;
    const int m0 = blockIdx.x * 128;

    #pragma unroll
    for (int i = 0; i < 8; ++i)
        ((float4*)Ws)[t + 256 * i] = ((const float4*)WT)[t + 256 * i];
    #pragma unroll
    for (int i = 0; i < 8; ++i) {
        const int idx = t + 256 * i;
        const int m = idx >> 4, kq = idx & 15;
        float4 v = make_float4(0.f, 0.f, 0.f, 0.f);
        if (m0 + m < M) v = nf4[(size_t)(m0 + m) * 16 + kq];
        As[swz(4 * kq + 0, m)] = v.x;
        As[swz(4 * kq + 1, m)] = v.y;
        As[swz(4 * kq + 2, m)] = v.z;
        As[swz(4 * kq + 3, m)] = v.w;
    }
    __syncthreads();

    float acc[8][8];
    #pragma unroll
    for (int ri = 0; ri < 8; ++ri)
        #pragma unroll
        for (int ci = 0; ci < 8; ++ci) acc[ri][ci] = 0.f;

    #pragma unroll 8
    for (int k = 0; k < 64; ++k) {
        const float4 aLo = *(const float4*)&As[swz(k, tr * 4)];
        const float4 aHi = *(const float4*)&As[swz(k, 64 + tr * 4)];
        const float4 bLo = *(const float4*)&Ws[k * 128 + tc * 4];
        const float4 bHi = *(const float4*)&Ws[k * 128 + 64 + tc * 4];
        const float av[8] = {aLo.x, aLo.y, aLo.z, aLo.w, aHi.x, aHi.y, aHi.z, aHi.w};
        const float bv[8] = {bLo.x, bLo.y, bLo.z, bLo.w, bHi.x, bHi.y, bHi.z, bHi.w};
        #pragma unroll
        for (int ri = 0; ri < 8; ++ri)
            #pragma unroll
            for (int ci = 0; ci < 8; ++ci) acc[ri][ci] += av[ri] * bv[ci];
    }

    #pragma unroll
    for (int ri = 0; ri < 8; ++ri) {
        const int v = m0 + ((ri < 4) ? (tr * 4 + ri) : (64 + tr * 4 + ri - 4));
        if (v < M) {
            H4 lo, hi;
            #pragma unroll
            for (int j = 0; j < 4; ++j) { lo.h[j] = (f16)acc[ri][j]; hi.h[j] = (f16)acc[ri][4 + j]; }
            *(short4*)&A16[(size_t)v * 64 + tc * 4] = lo.s;
            *(short4*)&B16[(size_t)v * 64 + tc * 4] = hi.s;
        }
    }
}

// ---------------- gemm_c: C = ef @ WT_c, tile 128x64, K=32 ----------------
__global__ __launch_bounds__(256) void gemm_c_kernel(
    const float4* __restrict__ ef4, const float* __restrict__ WT,
    f16* __restrict__ C16, int M)
{
    __shared__ float As[32 * 128];
    __shared__ float Ws[32 * 64];
    const int t = threadIdx.x;
    const int tr = t >> 4, tc = t & 15;
    const int m0 = blockIdx.x * 128;

    #pragma unroll
    for (int i = 0; i < 2; ++i)
        ((float4*)Ws)[t + 256 * i] = ((const float4*)WT)[t + 256 * i];
    #pragma unroll
    for (int i = 0; i < 4; ++i) {
        const int idx = t + 256 * i;
        const int m = idx >> 3, kq = idx & 7;
        float4 v = make_float4(0.f, 0.f, 0.f, 0.f);
        if (m0 + m < M) v = ef4[(size_t)(m0 + m) * 8 + kq];
        As[swz(4 * kq + 0, m)] = v.x;
        As[swz(4 * kq + 1, m)] = v.y;
        As[swz(4 * kq + 2, m)] = v.z;
        As[swz(4 * kq + 3, m)] = v.w;
    }
    __syncthreads();

    float acc[8][4];
    #pragma unroll
    for (int ri = 0; ri < 8; ++ri)
        #pragma unroll
        for (int ci = 0; ci < 4; ++ci) acc[ri][ci] = 0.f;

    #pragma unroll 8
    for (int k = 0; k < 32; ++k) {
        const float4 aLo = *(const float4*)&As[swz(k, tr * 4)];
        const float4 aHi = *(const float4*)&As[swz(k, 64 + tr * 4)];
        const float4 w  = *(const float4*)&Ws[k * 64 + tc * 4];
        const float av[8] = {aLo.x, aLo.y, aLo.z, aLo.w, aHi.x, aHi.y, aHi.z, aHi.w};
        const float bv[4] = {w.x, w.y, w.z, w.w};
        #pragma unroll
        for (int ri = 0; ri < 8; ++ri)
            #pragma unroll
            for (int ci = 0; ci < 4; ++ci) acc[ri][ci] += av[ri] * bv[ci];
    }

    #pragma unroll
    for (int ri = 0; ri < 8; ++ri) {
        const int v = m0 + ((ri < 4) ? (tr * 4 + ri) : (64 + tr * 4 + ri - 4));
        if (v < M) {
            H4 u;
            #pragma unroll
            for (int j = 0; j < 4; ++j) u.h[j] = (f16)acc[ri][j];
            *(short4*)&C16[(size_t)v * 64 + tc * 4] = u.s;
        }
    }
}

// ---------------- CSR build (XCD-partitioned) ----------------
__global__ __launch_bounds__(256) void hist_kernel(
    const int* __restrict__ src, const int* __restrict__ dst,
    int* __restrict__ cnt, int E, int N)
{
    const int part = blockIdx.x & 7;
    const int lo = (int)(((long long)N * part) >> 3);
    const int hi = (int)(((long long)N * (part + 1)) >> 3);
    const int tid = (blockIdx.x >> 3) * blockDim.x + threadIdx.x;
    const int tpp = (gridDim.x >> 3) * blockDim.x;
    const int E4 = E >> 2;
    const int4* src4 = (const int4*)src;
    const int4* dst4 = (const int4*)dst;
    for (int j = tid; j < E4; j += tpp) {
        const int4 s = src4[j], d = dst4[j];
        if (d.x >= lo && d.x < hi) atomicAdd(&cnt[d.x], 1);
        if (d.y >= lo && d.y < hi) atomicAdd(&cnt[d.y], 1);
        if (d.z >= lo && d.z < hi) atomicAdd(&cnt[d.z], 1);
        if (d.w >= lo && d.w < hi) atomicAdd(&cnt[d.w], 1);
        if (s.x >= lo && s.x < hi) atomicAdd(&cnt[s.x], 1);
        if (s.y >= lo && s.y < hi) atomicAdd(&cnt[s.y], 1);
        if (s.z >= lo && s.z < hi) atomicAdd(&cnt[s.z], 1);
        if (s.w >= lo && s.w < hi) atomicAdd(&cnt[s.w], 1);
    }
    for (int i = (E4 << 2) + tid; i < E; i += tpp) {
        const int s = src[i], d = dst[i];
        if (d >= lo && d < hi) atomicAdd(&cnt[d], 1);
        if (s >= lo && s < hi) atomicAdd(&cnt[s], 1);
    }
}

__global__ __launch_bounds__(256) void scan_a_kernel(
    const int* __restrict__ cnt, int* __restrict__ row, int* __restrict__ sums, int N)
{
    __shared__ int ls[256];
    const int t = threadIdx.x;
    const int base = blockIdx.x * 512;
    const int g0 = base + 2 * t, g1 = g0 + 1;
    const int x0 = (g0 < N) ? cnt[g0] : 0;
    const int x1 = (g1 < N) ? cnt[g1] : 0;
    const int s = x0 + x1;
    ls[t] = s;
    __syncthreads();
    #pragma unroll
    for (int off = 1; off < 256; off <<= 1) {
        int v = (t >= off) ? ls[t - off] : 0;
        __syncthreads();
        ls[t] += v;
        __syncthreads();
    }
    const int excl = ls[t] - s;
    if (g0 < N) row[g0] = excl;
    if (g1 < N) row[g1] = excl + x0;
    if (t == 255) sums[blockIdx.x] = ls[t];
}

__global__ __launch_bounds__(256) void scan_b_kernel(int* __restrict__ sums, int nb)
{
    __shared__ int ls[256];
    const int t = threadIdx.x;
    const int s = (t < nb) ? sums[t] : 0;
    ls[t] = s;
    __syncthreads();
    #pragma unroll
    for (int off = 1; off < 256; off <<= 1) {
        int v = (t >= off) ? ls[t - off] : 0;
        __syncthreads();
        ls[t] += v;
        __syncthreads();
    }
    if (t < nb) sums[t] = ls[t] - s;
}

__global__ void scan_c_kernel(int* __restrict__ row, int* __restrict__ ofs,
                              const int* __restrict__ sums, int2* __restrict__ inc,
                              int N, int total)
{
    const int i = blockIdx.x * blockDim.x + threadIdx.x;
    if (i < N) {
        const int r = row[i] + sums[i >> 9];
        row[i] = r;
        ofs[i] = r;
    }
    if (i == 0) {
        row[N] = total;
        inc[total + 0] = make_int2(0, 0);
        inc[total + 1] = make_int2(0, 0);
        inc[total + 2] = make_int2(0, 0);
        inc[total + 3] = make_int2(0, 0);
    }
}

// scatter stores BYTE offsets: (src_node<<7, edge_id<<7) — rows are 128B.
__global__ __launch_bounds__(256) void scatter_kernel(
    const int* __restrict__ src, const int* __restrict__ dst,
    int* __restrict__ ofs, int2* __restrict__ inc, int E, int N)
{
    const int part = blockIdx.x & 7;
    const int lo = (int)(((long long)N * part) >> 3);
    const int hi = (int)(((long long)N * (part + 1)) >> 3);
    const int tid = (blockIdx.x >> 3) * blockDim.x + threadIdx.x;
    const int tpp = (gridDim.x >> 3) * blockDim.x;
    const int E4 = E >> 2;
    const int4* src4 = (const int4*)src;
    const int4* dst4 = (const int4*)dst;
    for (int j = tid; j < E4; j += tpp) {
        const int4 s = src4[j], d = dst4[j];
        const int e0 = 4 * j;
        if (d.x >= lo && d.x < hi) { const int p = atomicAdd(&ofs[d.x], 1); inc[p] = make_int2(s.x << 7, (e0 + 0) << 7); }
        if (d.y >= lo && d.y < hi) { const int p = atomicAdd(&ofs[d.y], 1); inc[p] = make_int2(s.y << 7, (e0 + 1) << 7); }
        if (d.z >= lo && d.z < hi) { const int p = atomicAdd(&ofs[d.z], 1); inc[p] = make_int2(s.z << 7, (e0 + 2) << 7); }
        if (d.w >= lo && d.w < hi) { const int p = atomicAdd(&ofs[d.w], 1); inc[p] = make_int2(s.w << 7, (e0 + 3) << 7); }
        if (s.x >= lo && s.x < hi) { const int q = atomicAdd(&ofs[s.x], 1); inc[q] = make_int2(d.x << 7, (e0 + 0) << 7); }
        if (s.y >= lo && s.y < hi) { const int q = atomicAdd(&ofs[s.y], 1); inc[q] = make_int2(d.y << 7, (e0 + 1) << 7); }
        if (s.z >= lo && s.z < hi) { const int q = atomicAdd(&ofs[s.z], 1); inc[q] = make_int2(d.z << 7, (e0 + 2) << 7); }
        if (s.w >= lo && s.w < hi) { const int q = atomicAdd(&ofs[s.w], 1); inc[q] = make_int2(d.w << 7, (e0 + 3) << 7); }
    }
    for (int i = (E4 << 2) + tid; i < E; i += tpp) {
        const int s = src[i], d = dst[i];
        if (d >= lo && d < hi) { const int p = atomicAdd(&ofs[d], 1); inc[p] = make_int2(s << 7, i << 7); }
        if (s >= lo && s < hi) { const int q = atomicAdd(&ofs[s], 1); inc[q] = make_int2(d << 7, i << 7); }
    }
}

// ---------------- reduce: red[v] = sum leaky(A[u]+B[v]+C[e]) ----------------
// wave = 4 incidence slots (g = lane>>4) x 16 lanes (sub), 4 channels/lane.
// A/C gathers are dwordx2 (8B/lane, 128B per row per 16-lane group).
// Tail slots are zeroed via cndmask; inc[] is padded with 4 zero entries.
__global__ __launch_bounds__(256) void reduce_kernel(
    const f16* __restrict__ A16, const f16* __restrict__ B16,
    const f16* __restrict__ C16, const int* __restrict__ row,
    const int2* __restrict__ inc, float* __restrict__ red, int N)
{
    const int lane = threadIdx.x & 63;
    const int g = lane >> 4;        // incidence slot within wave
    const int sub = lane & 15;      // channel quad: ch = sub*4 .. sub*4+3
    const int sub8 = sub * 8;       // byte offset within a 128B f16 row
    const char* Ab = (const char*)A16;
    const char* Cb = (const char*)C16;
    const int gw = (blockIdx.x * blockDim.x + threadIdx.x) >> 6;
    const int W = (gridDim.x * blockDim.x) >> 6;
    for (int v = gw; v < N; v += W) {
        H4 bh; bh.s = *(const short4*)&B16[(size_t)v * 64 + sub * 4];
        const float b0 = (float)bh.h[0], b1 = (float)bh.h[1];
        const float b2 = (float)bh.h[2], b3 = (float)bh.h[3];
        const int beg = row[v], end = row[v + 1];
        float acc0 = 0.f, acc1 = 0.f, acc2 = 0.f, acc3 = 0.f;
        for (int i = beg; i < end; i += 4) {
            const int idx = i + g;
            H4 rr; rr.ll = __builtin_nontemporal_load((const long long*)&inc[idx]);
            const int2 r = *(const int2*)&rr.ll;
            H4 ah; ah.s = *(const short4*)(Ab + (size_t)(unsigned)r.x + sub8);
            H4 ch; ch.s = *(const short4*)(Cb + (size_t)(unsigned)r.y + sub8);
            float m0 = (float)ah.h[0] + b0 + (float)ch.h[0];
            float m1 = (float)ah.h[1] + b1 + (float)ch.h[1];
            float m2 = (float)ah.h[2] + b2 + (float)ch.h[2];
            float m3 = (float)ah.h[3] + b3 + (float)ch.h[3];
            m0 = LEAKY(m0); m1 = LEAKY(m1); m2 = LEAKY(m2); m3 = LEAKY(m3);
            const bool ok = idx < end;
            acc0 += ok ? m0 : 0.f;
            acc1 += ok ? m1 : 0.f;
            acc2 += ok ? m2 : 0.f;
            acc3 += ok ? m3 : 0.f;
        }
        acc0 += __shfl_xor(acc0, 16); acc0 += __shfl_xor(acc0, 32);
        acc1 += __shfl_xor(acc1, 16); acc1 += __shfl_xor(acc1, 32);
        acc2 += __shfl_xor(acc2, 16); acc2 += __shfl_xor(acc2, 32);
        acc3 += __shfl_xor(acc3, 16); acc3 += __shfl_xor(acc3, 32);
        if (lane < 16) {
            float4 o = make_float4(acc0, acc1, acc2, acc3);
            *(float4*)&red[(size_t)v * 64 + sub * 4] = o;
        }
    }
}

// ---------------- apply: out = leaky([nf|red] @ WT_n), tile 128x64, K=128 ----------------
__global__ __launch_bounds__(256) void apply_kernel(
    const float4* __restrict__ nf4, const float4* __restrict__ red4,
    const float* __restrict__ WT, float* __restrict__ out, int M)
{
    __shared__ float As[64 * 128];
    __shared__ float Ws[128 * 64];
    const int t = threadIdx.x;
    const int tr = t >> 4, tc = t & 15;
    const int m0 = blockIdx.x * 128;

    #pragma unroll
    for (int i = 0; i < 8; ++i)
        ((float4*)Ws)[t + 256 * i] = ((const float4*)WT)[t + 256 * i];

    float acc[8][4];
    #pragma unroll
    for (int ri = 0; ri < 8; ++ri)
        #pragma unroll
        for (int ci = 0; ci < 4; ++ci) acc[ri][ci] = 0.f;

    for (int h = 0; h < 2; ++h) {
        const float4* __restrict__ src = h ? red4 : nf4;
        #pragma unroll
        for (int i = 0; i < 8; ++i) {
            const int idx = t + 256 * i;
            const int m = idx >> 4, kq = idx & 15;
            float4 v = make_float4(0.f, 0.f, 0.f, 0.f);
            if (m0 + m < M) v = src[(size_t)(m0 + m) * 16 + kq];
            As[swz(4 * kq + 0, m)] = v.x;
            As[swz(4 * kq + 1, m)] = v.y;
            As[swz(4 * kq + 2, m)] = v.z;
            As[swz(4 * kq + 3, m)] = v.w;
        }
        __syncthreads();
        #pragma unroll 8
        for (int k = 0; k < 64; ++k) {
            const float4 aLo = *(const float4*)&As[swz(k, tr * 4)];
            const float4 aHi = *(const float4*)&As[swz(k, 64 + tr * 4)];
            const float4 w  = *(const float4*)&Ws[(h * 64 + k) * 64 + tc * 4];
            const float av[8] = {aLo.x, aLo.y, aLo.z, aLo.w, aHi.x, aHi.y, aHi.z, aHi.w};
            const float bv[4] = {w.x, w.y, w.z, w.w};
            #pragma unroll
            for (int ri = 0; ri < 8; ++ri)
                #pragma unroll
                for (int ci = 0; ci < 4; ++ci) acc[ri][ci] += av[ri] * bv[ci];
        }
        __syncthreads();
    }

    #pragma unroll
    for (int ri = 0; ri < 8; ++ri) {
        const int v = m0 + ((ri < 4) ? (tr * 4 + ri) : (64 + tr * 4 + ri - 4));
        if (v < M) {
            float4 o;
            o.x = LEAKY(acc[ri][0]); o.y = LEAKY(acc[ri][1]);
            o.z = LEAKY(acc[ri][2]); o.w = LEAKY(acc[ri][3]);
            *(float4*)&out[(size_t)v * 64 + tc * 4] = o;
        }
    }
}

extern "C" void kernel_launch(void* const* d_in, const int* in_sizes, int n_in,
                              void* d_out, int out_size, void* d_ws, size_t ws_size,
                              hipStream_t stream) {
    const float* nf  = (const float*)d_in[0];   // [N,64]
    const float* ef  = (const float*)d_in[1];   // [E,32]
    const int*   src = (const int*)d_in[2];     // [E]
    const int*   dst = (const int*)d_in[3];     // [E]
    const float* We  = (const float*)d_in[4];   // [64,160]
    const float* Wn  = (const float*)d_in[5];   // [64,128]

    const int N = in_sizes[0] / 64;
    const int E = in_sizes[2];

    char* p = (char*)d_ws;
    auto alloc = [&](size_t bytes) -> char* {
        char* r = p; p += (bytes + 255) & ~(size_t)255; return r;
    };
    float* red  = (float*)alloc((size_t)N * 64 * 4);
    float* WTab = (float*)alloc(8192 * 4);
    float* WTc  = (float*)alloc(2048 * 4);
    float* WTn  = (float*)alloc(8192 * 4);
    int2*  inc  = (int2*)alloc(((size_t)2 * E + 4) * 8);
    int*   cnt  = (int*)alloc((size_t)N * 4);
    int*   row  = (int*)alloc(((size_t)N + 1) * 4);
    int*   sums = (int*)alloc(256 * 4);
    int*   ofs  = (int*)alloc((size_t)N * 4);
    f16*   A16  = (f16*)alloc((size_t)N * 64 * 2);
    f16*   B16  = (f16*)alloc((size_t)N * 64 * 2);
    f16*   C16  = (f16*)alloc((size_t)E * 64 * 2);

    hipMemsetAsync(cnt, 0, (size_t)N * sizeof(int), stream);
    prep_weights_kernel<<<36, 256, 0, stream>>>(We, Wn, WTab, WTc, WTn);
    gemm_ab_kernel<<<(N + 127) / 128, 256, 0, stream>>>((const float4*)nf, WTab, A16, B16, N);
    gemm_c_kernel<<<(E + 127) / 128, 256, 0, stream>>>((const float4*)ef, WTc, C16, E);
    hist_kernel<<<2048, 256, 0, stream>>>(src, dst, cnt, E, N);
    const int nb = (N + 511) / 512;
    scan_a_kernel<<<nb, 256, 0, stream>>>(cnt, row, sums, N);
    scan_b_kernel<<<1, 256, 0, stream>>>(sums, nb);
    scan_c_kernel<<<(N + 255) / 256, 256, 0, stream>>>(row, ofs, sums, inc, N, 2 * E);
    scatter_kernel<<<2048, 256, 0, stream>>>(src, dst, ofs, inc, E, N);
    reduce_kernel<<<2048, 256, 0, stream>>>(A16, B16, C16, row, inc, red, N);
    apply_kernel<<<(N + 127) / 128, 256, 0, stream>>>((const float4*)nf, (const float4*)red,
                                                      WTn, (float*)d_out, N);
}

// Round 2
// 362.625 us; speedup vs baseline: 1.0315x; 1.0315x over previous
//
#include <hip/hip_runtime.h>
#include <stdint.h>

// GNN layer, fp32, GEMM-restructured + CSR reduce:
//   prep: transpose weights into WT_ab[64][128], WT_c[32][64], WT_n[128][64]
//   gemm_ab: [A16|B16] = nf @ We[:,0:128]^T          (fp16 out, [N,64] each)
//   gemm_c:  C16 = ef @ We[:,128:160]^T              (fp16 out, [E,64])
//   CSR build: hist -> scan -> scatter, XCD-partitioned (blockIdx&7 owns a
//     node range; all stores/atomics for a line come from one XCD -> kills
//     the 8x partial-line writeback amplification measured in R5)
//     scatter stores BYTE offsets (src<<7, eid<<7) so reduce does no muls.
//   reduce:  red[v] = sum leaky(A16[u] + B16[v] + C16[e])   (fp32 acc)
//     wave = 4 groups x 16 lanes, 4 ch/lane. Unroll: 16 incidences/iter
//     (2x int4 inc loads + 8 independent short4 row-gathers in flight
//     -> ~1KB/wave outstanding; R1's 2-gather version was latency-bound
//     at 2.6 TB/s). Range predicate is one unsigned cmp; segment base
//     aligned to even so int4 inc loads stay 16B-aligned.
//   apply:   out = leaky(nf @ Wn[:,0:64]^T + red @ Wn[:,64:128]^T)

#define LEAKY(x) fmaxf((x), 0.01f * (x))
typedef _Float16 f16;

static __device__ __forceinline__ int swz(int k, int c) {
    return k * 128 + (c ^ (((k >> 2) & 7) << 2));
}

union H4 { f16 h[4]; short4 s; long long ll; };

// ---------------- weight prep (transpose into ws) ----------------
__global__ void prep_weights_kernel(const float* __restrict__ We,
                                    const float* __restrict__ Wn,
                                    float* __restrict__ WTab,
                                    float* __restrict__ WTc,
                                    float* __restrict__ WTn)
{
    int i = blockIdx.x * blockDim.x + threadIdx.x;
    const int stride = gridDim.x * blockDim.x;
    for (; i < 8192 + 2048 + 8192; i += stride) {
        if (i < 8192) {
            int k = i >> 7, n = i & 127;
            WTab[i] = We[(n & 63) * 160 + (n >> 6) * 64 + k];
        } else if (i < 10240) {
            int j = i - 8192; int k = j >> 6, n = j & 63;
            WTc[j] = We[n * 160 + 128 + k];
        } else {
            int j = i - 10240; int k = j >> 6, n = j & 63;
            WTn[j] = Wn[n * 128 + k];
        }
    }
}

// ---------------- gemm_ab: [A|B] = nf @ WT_ab, tile 128x128, K=64 ----------------
__global__ __launch_bounds__(256) void gemm_ab_kernel(
    const float4* __restrict__ nf4, const float* __restrict__ WT,
    f16* __restrict__ A16, f16* __restrict__ B16, int M)
{
    __shared__ float As[64 * 128];
    __shared__ float Ws[64 * 128];
    const int t = threadIdx.x;
    const int tr = t >> 4, tc = t & 15;
    const int m0 = blockIdx.x * 128;

    #pragma unroll
    for (int i = 0; i < 8; ++i)
        ((float4*)Ws)[t + 256 * i] = ((const float4*)WT)[t + 256 * i];
    #pragma unroll
    for (int i = 0; i < 8; ++i) {
        const int idx = t + 256 * i;
        const int m = idx >> 4, kq = idx & 15;
        float4 v = make_float4(0.f, 0.f, 0.f, 0.f);
        if (m0 + m < M) v = nf4[(size_t)(m0 + m) * 16 + kq];
        As[swz(4 * kq + 0, m)] = v.x;
        As[swz(4 * kq + 1, m)] = v.y;
        As[swz(4 * kq + 2, m)] = v.z;
        As[swz(4 * kq + 3, m)] = v.w;
    }
    __syncthreads();

    float acc[8][8];
    #pragma unroll
    for (int ri = 0; ri < 8; ++ri)
        #pragma unroll
        for (int ci = 0; ci < 8; ++ci) acc[ri][ci] = 0.f;

    #pragma unroll 8
    for (int k = 0; k < 64; ++k) {
        const float4 aLo = *(const float4*)&As[swz(k, tr * 4)];
        const float4 aHi = *(const float4*)&As[swz(k, 64 + tr * 4)];
        const float4 bLo = *(const float4*)&Ws[k * 128 + tc * 4];
        const float4 bHi = *(const float4*)&Ws[k * 128 + 64 + tc * 4];
        const float av[8] = {aLo.x, aLo.y, aLo.z, aLo.w, aHi.x, aHi.y, aHi.z, aHi.w};
        const float bv[8] = {bLo.x, bLo.y, bLo.z, bLo.w, bHi.x, bHi.y, bHi.z, bHi.w};
        #pragma unroll
        for (int ri = 0; ri < 8; ++ri)
            #pragma unroll
            for (int ci = 0; ci < 8; ++ci) acc[ri][ci] += av[ri] * bv[ci];
    }

    #pragma unroll
    for (int ri = 0; ri < 8; ++ri) {
        const int v = m0 + ((ri < 4) ? (tr * 4 + ri) : (64 + tr * 4 + ri - 4));
        if (v < M) {
            H4 lo, hi;
            #pragma unroll
            for (int j = 0; j < 4; ++j) { lo.h[j] = (f16)acc[ri][j]; hi.h[j] = (f16)acc[ri][4 + j]; }
            *(short4*)&A16[(size_t)v * 64 + tc * 4] = lo.s;
            *(short4*)&B16[(size_t)v * 64 + tc * 4] = hi.s;
        }
    }
}

// ---------------- gemm_c: C = ef @ WT_c, tile 128x64, K=32 ----------------
__global__ __launch_bounds__(256) void gemm_c_kernel(
    const float4* __restrict__ ef4, const float* __restrict__ WT,
    f16* __restrict__ C16, int M)
{
    __shared__ float As[32 * 128];
    __shared__ float Ws[32 * 64];
    const int t = threadIdx.x;
    const int tr = t >> 4, tc = t & 15;
    const int m0 = blockIdx.x * 128;

    #pragma unroll
    for (int i = 0; i < 2; ++i)
        ((float4*)Ws)[t + 256 * i] = ((const float4*)WT)[t + 256 * i];
    #pragma unroll
    for (int i = 0; i < 4; ++i) {
        const int idx = t + 256 * i;
        const int m = idx >> 3, kq = idx & 7;
        float4 v = make_float4(0.f, 0.f, 0.f, 0.f);
        if (m0 + m < M) v = ef4[(size_t)(m0 + m) * 8 + kq];
        As[swz(4 * kq + 0, m)] = v.x;
        As[swz(4 * kq + 1, m)] = v.y;
        As[swz(4 * kq + 2, m)] = v.z;
        As[swz(4 * kq + 3, m)] = v.w;
    }
    __syncthreads();

    float acc[8][4];
    #pragma unroll
    for (int ri = 0; ri < 8; ++ri)
        #pragma unroll
        for (int ci = 0; ci < 4; ++ci) acc[ri][ci] = 0.f;

    #pragma unroll 8
    for (int k = 0; k < 32; ++k) {
        const float4 aLo = *(const float4*)&As[swz(k, tr * 4)];
        const float4 aHi = *(const float4*)&As[swz(k, 64 + tr * 4)];
        const float4 w  = *(const float4*)&Ws[k * 64 + tc * 4];
        const float av[8] = {aLo.x, aLo.y, aLo.z, aLo.w, aHi.x, aHi.y, aHi.z, aHi.w};
        const float bv[4] = {w.x, w.y, w.z, w.w};
        #pragma unroll
        for (int ri = 0; ri < 8; ++ri)
            #pragma unroll
            for (int ci = 0; ci < 4; ++ci) acc[ri][ci] += av[ri] * bv[ci];
    }

    #pragma unroll
    for (int ri = 0; ri < 8; ++ri) {
        const int v = m0 + ((ri < 4) ? (tr * 4 + ri) : (64 + tr * 4 + ri - 4));
        if (v < M) {
            H4 u;
            #pragma unroll
            for (int j = 0; j < 4; ++j) u.h[j] = (f16)acc[ri][j];
            *(short4*)&C16[(size_t)v * 64 + tc * 4] = u.s;
        }
    }
}

// ---------------- CSR build (XCD-partitioned) ----------------
__global__ __launch_bounds__(256) void hist_kernel(
    const int* __restrict__ src, const int* __restrict__ dst,
    int* __restrict__ cnt, int E, int N)
{
    const int part = blockIdx.x & 7;
    const int lo = (int)(((long long)N * part) >> 3);
    const int hi = (int)(((long long)N * (part + 1)) >> 3);
    const int tid = (blockIdx.x >> 3) * blockDim.x + threadIdx.x;
    const int tpp = (gridDim.x >> 3) * blockDim.x;
    const int E4 = E >> 2;
    const int4* src4 = (const int4*)src;
    const int4* dst4 = (const int4*)dst;
    for (int j = tid; j < E4; j += tpp) {
        const int4 s = src4[j], d = dst4[j];
        if (d.x >= lo && d.x < hi) atomicAdd(&cnt[d.x], 1);
        if (d.y >= lo && d.y < hi) atomicAdd(&cnt[d.y], 1);
        if (d.z >= lo && d.z < hi) atomicAdd(&cnt[d.z], 1);
        if (d.w >= lo && d.w < hi) atomicAdd(&cnt[d.w], 1);
        if (s.x >= lo && s.x < hi) atomicAdd(&cnt[s.x], 1);
        if (s.y >= lo && s.y < hi) atomicAdd(&cnt[s.y], 1);
        if (s.z >= lo && s.z < hi) atomicAdd(&cnt[s.z], 1);
        if (s.w >= lo && s.w < hi) atomicAdd(&cnt[s.w], 1);
    }
    for (int i = (E4 << 2) + tid; i < E; i += tpp) {
        const int s = src[i], d = dst[i];
        if (d >= lo && d < hi) atomicAdd(&cnt[d], 1);
        if (s >= lo && s < hi) atomicAdd(&cnt[s], 1);
    }
}

__global__ __launch_bounds__(256) void scan_a_kernel(
    const int* __restrict__ cnt, int* __restrict__ row, int* __restrict__ sums, int N)
{
    __shared__ int ls[256];
    const int t = threadIdx.x;
    const int base = blockIdx.x * 512;
    const int g0 = base + 2 * t, g1 = g0 + 1;
    const int x0 = (g0 < N) ? cnt[g0] : 0;
    const int x1 = (g1 < N) ? cnt[g1] : 0;
    const int s = x0 + x1;
    ls[t] = s;
    __syncthreads();
    #pragma unroll
    for (int off = 1; off < 256; off <<= 1) {
        int v = (t >= off) ? ls[t - off] : 0;
        __syncthreads();
        ls[t] += v;
        __syncthreads();
    }
    const int excl = ls[t] - s;
    if (g0 < N) row[g0] = excl;
    if (g1 < N) row[g1] = excl + x0;
    if (t == 255) sums[blockIdx.x] = ls[t];
}

__global__ __launch_bounds__(256) void scan_b_kernel(int* __restrict__ sums, int nb)
{
    __shared__ int ls[256];
    const int t = threadIdx.x;
    const int s = (t < nb) ? sums[t] : 0;
    ls[t] = s;
    __syncthreads();
    #pragma unroll
    for (int off = 1; off < 256; off <<= 1) {
        int v = (t >= off) ? ls[t - off] : 0;
        __syncthreads();
        ls[t] += v;
        __syncthreads();
    }
    if (t < nb) sums[t] = ls[t] - s;
}

__global__ void scan_c_kernel(int* __restrict__ row, int* __restrict__ ofs,
                              const int* __restrict__ sums, int2* __restrict__ inc,
                              int N, int total)
{
    const int i = blockIdx.x * blockDim.x + threadIdx.x;
    if (i < N) {
        const int r = row[i] + sums[i >> 9];
        row[i] = r;
        ofs[i] = r;
    }
    if (i == 0) {
        row[N] = total;
        #pragma unroll
        for (int t = 0; t < 16; ++t) inc[total + t] = make_int2(0, 0);
    }
}

// scatter stores BYTE offsets: (src_node<<7, edge_id<<7) — rows are 128B.
__global__ __launch_bounds__(256) void scatter_kernel(
    const int* __restrict__ src, const int* __restrict__ dst,
    int* __restrict__ ofs, int2* __restrict__ inc, int E, int N)
{
    const int part = blockIdx.x & 7;
    const int lo = (int)(((long long)N * part) >> 3);
    const int hi = (int)(((long long)N * (part + 1)) >> 3);
    const int tid = (blockIdx.x >> 3) * blockDim.x + threadIdx.x;
    const int tpp = (gridDim.x >> 3) * blockDim.x;
    const int E4 = E >> 2;
    const int4* src4 = (const int4*)src;
    const int4* dst4 = (const int4*)dst;
    for (int j = tid; j < E4; j += tpp) {
        const int4 s = src4[j], d = dst4[j];
        const int e0 = 4 * j;
        if (d.x >= lo && d.x < hi) { const int p = atomicAdd(&ofs[d.x], 1); inc[p] = make_int2(s.x << 7, (e0 + 0) << 7); }
        if (d.y >= lo && d.y < hi) { const int p = atomicAdd(&ofs[d.y], 1); inc[p] = make_int2(s.y << 7, (e0 + 1) << 7); }
        if (d.z >= lo && d.z < hi) { const int p = atomicAdd(&ofs[d.z], 1); inc[p] = make_int2(s.z << 7, (e0 + 2) << 7); }
        if (d.w >= lo && d.w < hi) { const int p = atomicAdd(&ofs[d.w], 1); inc[p] = make_int2(s.w << 7, (e0 + 3) << 7); }
        if (s.x >= lo && s.x < hi) { const int q = atomicAdd(&ofs[s.x], 1); inc[q] = make_int2(d.x << 7, (e0 + 0) << 7); }
        if (s.y >= lo && s.y < hi) { const int q = atomicAdd(&ofs[s.y], 1); inc[q] = make_int2(d.y << 7, (e0 + 1) << 7); }
        if (s.z >= lo && s.z < hi) { const int q = atomicAdd(&ofs[s.z], 1); inc[q] = make_int2(d.z << 7, (e0 + 2) << 7); }
        if (s.w >= lo && s.w < hi) { const int q = atomicAdd(&ofs[s.w], 1); inc[q] = make_int2(d.w << 7, (e0 + 3) << 7); }
    }
    for (int i = (E4 << 2) + tid; i < E; i += tpp) {
        const int s = src[i], d = dst[i];
        if (d >= lo && d < hi) { const int p = atomicAdd(&ofs[d], 1); inc[p] = make_int2(s << 7, i << 7); }
        if (s >= lo && s < hi) { const int q = atomicAdd(&ofs[s], 1); inc[q] = make_int2(d << 7, i << 7); }
    }
}

// ---------------- reduce: red[v] = sum leaky(A[u]+B[v]+C[e]) ----------------
// wave = 4 groups (g = lane>>4) x 16 lanes (sub = channel quad).
// Per iter: 16 incidences. Group g owns entries {i+2g, i+2g+1, i+8+2g,
// i+8+2g+1} via two int4 loads (16B-aligned since i is even), then 8
// independent short4 row-gathers -> ~1KB/wave in flight (MLP restored).
// Predicate: (unsigned)(ek - beg) < (unsigned)(end - beg) — one cmp, also
// masks the front-alignment slot. f16 packed pre-add a+c, then f32 + b.
__global__ __launch_bounds__(256) void reduce_kernel(
    const f16* __restrict__ A16, const f16* __restrict__ B16,
    const f16* __restrict__ C16, const int* __restrict__ row,
    const int2* __restrict__ inc, float* __restrict__ red, int N)
{
    const int lane = threadIdx.x & 63;
    const int g = lane >> 4;        // incidence group
    const int sub = lane & 15;      // channel quad: ch = sub*4 .. sub*4+3
    const int sub8 = sub * 8;       // byte offset within a 128B f16 row
    const char* Ab = (const char*)A16;
    const char* Cb = (const char*)C16;
    const int gw = (blockIdx.x * blockDim.x + threadIdx.x) >> 6;
    const int W = (gridDim.x * blockDim.x) >> 6;
    for (int v = gw; v < N; v += W) {
        H4 bh; bh.s = *(const short4*)&B16[(size_t)v * 64 + sub * 4];
        const float b0 = (float)bh.h[0], b1 = (float)bh.h[1];
        const float b2 = (float)bh.h[2], b3 = (float)bh.h[3];
        const int beg = row[v], end = row[v + 1];
        const unsigned len = (unsigned)(end - beg);
        const int ib = beg & ~1;    // even base -> int4 inc loads aligned
        float acc0 = 0.f, acc1 = 0.f, acc2 = 0.f, acc3 = 0.f;
        for (int i = ib; i < end; i += 16) {
            const int e0 = i + 2 * g;       // entries e0, e0+1
            const int e2 = e0 + 8;          // entries e2, e2+1
            const int4 q0 = *(const int4*)&inc[e0];
            const int4 q1 = *(const int4*)&inc[e2];
            H4 a0; a0.s = *(const short4*)(Ab + (size_t)(unsigned)q0.x + sub8);
            H4 c0; c0.s = *(const short4*)(Cb + (size_t)(unsigned)q0.y + sub8);
            H4 a1; a1.s = *(const short4*)(Ab + (size_t)(unsigned)q0.z + sub8);
            H4 c1; c1.s = *(const short4*)(Cb + (size_t)(unsigned)q0.w + sub8);
            H4 a2; a2.s = *(const short4*)(Ab + (size_t)(unsigned)q1.x + sub8);
            H4 c2; c2.s = *(const short4*)(Cb + (size_t)(unsigned)q1.y + sub8);
            H4 a3; a3.s = *(const short4*)(Ab + (size_t)(unsigned)q1.z + sub8);
            H4 c3; c3.s = *(const short4*)(Cb + (size_t)(unsigned)q1.w + sub8);
            {
                const bool ok = (unsigned)(e0 - beg) < len;
                float m0 = (float)(a0.h[0] + c0.h[0]) + b0; m0 = LEAKY(m0);
                float m1 = (float)(a0.h[1] + c0.h[1]) + b1; m1 = LEAKY(m1);
                float m2 = (float)(a0.h[2] + c0.h[2]) + b2; m2 = LEAKY(m2);
                float m3 = (float)(a0.h[3] + c0.h[3]) + b3; m3 = LEAKY(m3);
                acc0 += ok ? m0 : 0.f; acc1 += ok ? m1 : 0.f;
                acc2 += ok ? m2 : 0.f; acc3 += ok ? m3 : 0.f;
            }
            {
                const bool ok = (unsigned)(e0 + 1 - beg) < len;
                float m0 = (float)(a1.h[0] + c1.h[0]) + b0; m0 = LEAKY(m0);
                float m1 = (float)(a1.h[1] + c1.h[1]) + b1; m1 = LEAKY(m1);
                float m2 = (float)(a1.h[2] + c1.h[2]) + b2; m2 = LEAKY(m2);
                float m3 = (float)(a1.h[3] + c1.h[3]) + b3; m3 = LEAKY(m3);
                acc0 += ok ? m0 : 0.f; acc1 += ok ? m1 : 0.f;
                acc2 += ok ? m2 : 0.f; acc3 += ok ? m3 : 0.f;
            }
            {
                const bool ok = (unsigned)(e2 - beg) < len;
                float m0 = (float)(a2.h[0] + c2.h[0]) + b0; m0 = LEAKY(m0);
                float m1 = (float)(a2.h[1] + c2.h[1]) + b1; m1 = LEAKY(m1);
                float m2 = (float)(a2.h[2] + c2.h[2]) + b2; m2 = LEAKY(m2);
                float m3 = (float)(a2.h[3] + c2.h[3]) + b3; m3 = LEAKY(m3);
                acc0 += ok ? m0 : 0.f; acc1 += ok ? m1 : 0.f;
                acc2 += ok ? m2 : 0.f; acc3 += ok ? m3 : 0.f;
            }
            {
                const bool ok = (unsigned)(e2 + 1 - beg) < len;
                float m0 = (float)(a3.h[0] + c3.h[0]) + b0; m0 = LEAKY(m0);
                float m1 = (float)(a3.h[1] + c3.h[1]) + b1; m1 = LEAKY(m1);
                float m2 = (float)(a3.h[2] + c3.h[2]) + b2; m2 = LEAKY(m2);
                float m3 = (float)(a3.h[3] + c3.h[3]) + b3; m3 = LEAKY(m3);
                acc0 += ok ? m0 : 0.f; acc1 += ok ? m1 : 0.f;
                acc2 += ok ? m2 : 0.f; acc3 += ok ? m3 : 0.f;
            }
        }
        acc0 += __shfl_xor(acc0, 16); acc0 += __shfl_xor(acc0, 32);
        acc1 += __shfl_xor(acc1, 16); acc1 += __shfl_xor(acc1, 32);
        acc2 += __shfl_xor(acc2, 16); acc2 += __shfl_xor(acc2, 32);
        acc3 += __shfl_xor(acc3, 16); acc3 += __shfl_xor(acc3, 32);
        if (lane < 16) {
            float4 o = make_float4(acc0, acc1, acc2, acc3);
            *(float4*)&red[(size_t)v * 64 + sub * 4] = o;
        }
    }
}

// ---------------- apply: out = leaky([nf|red] @ WT_n), tile 128x64, K=128 ----------------
__global__ __launch_bounds__(256) void apply_kernel(
    const float4* __restrict__ nf4, const float4* __restrict__ red4,
    const float* __restrict__ WT, float* __restrict__ out, int M)
{
    __shared__ float As[64 * 128];
    __shared__ float Ws[128 * 64];
    const int t = threadIdx.x;
    const int tr = t >> 4, tc = t & 15;
    const int m0 = blockIdx.x * 128;

    #pragma unroll
    for (int i = 0; i < 8; ++i)
        ((float4*)Ws)[t + 256 * i] = ((const float4*)WT)[t + 256 * i];

    float acc[8][4];
    #pragma unroll
    for (int ri = 0; ri < 8; ++ri)
        #pragma unroll
        for (int ci = 0; ci < 4; ++ci) acc[ri][ci] = 0.f;

    for (int h = 0; h < 2; ++h) {
        const float4* __restrict__ src = h ? red4 : nf4;
        #pragma unroll
        for (int i = 0; i < 8; ++i) {
            const int idx = t + 256 * i;
            const int m = idx >> 4, kq = idx & 15;
            float4 v = make_float4(0.f, 0.f, 0.f, 0.f);
            if (m0 + m < M) v = src[(size_t)(m0 + m) * 16 + kq];
            As[swz(4 * kq + 0, m)] = v.x;
            As[swz(4 * kq + 1, m)] = v.y;
            As[swz(4 * kq + 2, m)] = v.z;
            As[swz(4 * kq + 3, m)] = v.w;
        }
        __syncthreads();
        #pragma unroll 8
        for (int k = 0; k < 64; ++k) {
            const float4 aLo = *(const float4*)&As[swz(k, tr * 4)];
            const float4 aHi = *(const float4*)&As[swz(k, 64 + tr * 4)];
            const float4 w  = *(const float4*)&Ws[(h * 64 + k) * 64 + tc * 4];
            const float av[8] = {aLo.x, aLo.y, aLo.z, aLo.w, aHi.x, aHi.y, aHi.z, aHi.w};
            const float bv[4] = {w.x, w.y, w.z, w.w};
            #pragma unroll
            for (int ri = 0; ri < 8; ++ri)
                #pragma unroll
                for (int ci = 0; ci < 4; ++ci) acc[ri][ci] += av[ri] * bv[ci];
        }
        __syncthreads();
    }

    #pragma unroll
    for (int ri = 0; ri < 8; ++ri) {
        const int v = m0 + ((ri < 4) ? (tr * 4 + ri) : (64 + tr * 4 + ri - 4));
        if (v < M) {
            float4 o;
            o.x = LEAKY(acc[ri][0]); o.y = LEAKY(acc[ri][1]);
            o.z = LEAKY(acc[ri][2]); o.w = LEAKY(acc[ri][3]);
            *(float4*)&out[(size_t)v * 64 + tc * 4] = o;
        }
    }
}

extern "C" void kernel_launch(void* const* d_in, const int* in_sizes, int n_in,
                              void* d_out, int out_size, void* d_ws, size_t ws_size,
                              hipStream_t stream) {
    const float* nf  = (const float*)d_in[0];   // [N,64]
    const float* ef  = (const float*)d_in[1];   // [E,32]
    const int*   src = (const int*)d_in[2];     // [E]
    const int*   dst = (const int*)d_in[3];     // [E]
    const float* We  = (const float*)d_in[4];   // [64,160]
    const float* Wn  = (const float*)d_in[5];   // [64,128]

    const int N = in_sizes[0] / 64;
    const int E = in_sizes[2];

    char* p = (char*)d_ws;
    auto alloc = [&](size_t bytes) -> char* {
        char* r = p; p += (bytes + 255) & ~(size_t)255; return r;
    };
    float* red  = (float*)alloc((size_t)N * 64 * 4);
    float* WTab = (float*)alloc(8192 * 4);
    float* WTc  = (float*)alloc(2048 * 4);
    float* WTn  = (float*)alloc(8192 * 4);
    int2*  inc  = (int2*)alloc(((size_t)2 * E + 16) * 8);
    int*   cnt  = (int*)alloc((size_t)N * 4);
    int*   row  = (int*)alloc(((size_t)N + 1) * 4);
    int*   sums = (int*)alloc(256 * 4);
    int*   ofs  = (int*)alloc((size_t)N * 4);
    f16*   A16  = (f16*)alloc((size_t)N * 64 * 2);
    f16*   B16  = (f16*)alloc((size_t)N * 64 * 2);
    f16*   C16  = (f16*)alloc((size_t)E * 64 * 2);

    hipMemsetAsync(cnt, 0, (size_t)N * sizeof(int), stream);
    prep_weights_kernel<<<36, 256, 0, stream>>>(We, Wn, WTab, WTc, WTn);
    gemm_ab_kernel<<<(N + 127) / 128, 256, 0, stream>>>((const float4*)nf, WTab, A16, B16, N);
    gemm_c_kernel<<<(E + 127) / 128, 256, 0, stream>>>((const float4*)ef, WTc, C16, E);
    hist_kernel<<<2048, 256, 0, stream>>>(src, dst, cnt, E, N);
    const int nb = (N + 511) / 512;
    scan_a_kernel<<<nb, 256, 0, stream>>>(cnt, row, sums, N);
    scan_b_kernel<<<1, 256, 0, stream>>>(sums, nb);
    scan_c_kernel<<<(N + 255) / 256, 256, 0, stream>>>(row, ofs, sums, inc, N, 2 * E);
    scatter_kernel<<<2048, 256, 0, stream>>>(src, dst, ofs, inc, E, N);
    reduce_kernel<<<2048, 256, 0, stream>>>(A16, B16, C16, row, inc, red, N);
    apply_kernel<<<(N + 127) / 128, 256, 0, stream>>>((const float4*)nf, (const float4*)red,
                                                      WTn, (float*)d_out, N);
}